// Round 12
// baseline (128.425 us; speedup 1.0000x reference)
//
#include <hip/hip_runtime.h>
#include <math.h>
#include <stdint.h>

#define NB 16
#define NN 50000
#define NC 8
#define ND 2
#define MAX_DET 300
#define NMS_T 0.5f
#define SCORE_T 0.05f
#define CAP 1024
#define CUTBIN 252        // s >= 0.984375 ; E[cnt]=781 +- 28
#define LBUF 128
#define BIGM 512
#define CHUNK 128
#define NT 512
#define NPI (NN * NC)
#define CBLK 32
#define F4PB (NPI / 4 / CBLK)

typedef unsigned long long u64;

__device__ __forceinline__ float neg_inf() { return -__builtin_inff(); }

// Bit-exact IoU > 0.5, division-free (see R11 proof; validated absmax 0).
__device__ __forceinline__ bool iou_gt(float ax1, float ay1, float ax2, float ay2,
                                       float area_a,
                                       float bx1, float by1, float bx2, float by2) {
    float x1 = fmaxf(ax1, bx1), y1 = fmaxf(ay1, by1);
    float x2 = fminf(ax2, bx2), y2 = fminf(ay2, by2);
    float inter = __fmul_rn(fmaxf(__fsub_rn(x2, x1), 0.0f),
                            fmaxf(__fsub_rn(y2, y1), 0.0f));
    float area_b = __fmul_rn(__fsub_rn(bx2, bx1), __fsub_rn(by2, by1));
    float uni = __fsub_rn(__fadd_rn(area_a, area_b), inter);
    return inter > __fmul_rn(0.5f, fmaxf(uni, 1e-8f));
}

__device__ __forceinline__ u64 score_key(float s, int n) {
    unsigned u = __float_as_uint(s);
    u ^= (u & 0x80000000u) ? 0xFFFFFFFFu : 0x80000000u;
    return ((u64)u << 32) | (unsigned)(~(unsigned)n);
}

__device__ __forceinline__ u64 shfl_xor_u64(u64 v, int m) {
    unsigned lo = (unsigned)v, hi = (unsigned)(v >> 32);
    lo = __shfl_xor(lo, m, 64);
    hi = __shfl_xor(hi, m, 64);
    return ((u64)hi << 32) | lo;
}

// ---------------- C: coalesced fixed-threshold compaction -----------------
__global__ __launch_bounds__(1024) void compact_kernel(
    const float* __restrict__ cls, int* __restrict__ cnt_g,
    u64* __restrict__ cand)
{
    const int b = blockIdx.x >> 5, t32 = blockIdx.x & 31;
    const int tid = threadIdx.x;
    __shared__ u64 buf[8][LBUF];
    __shared__ int lcnt[8], gbase[8];
    if (tid < 8) lcnt[tid] = 0;
    __syncthreads();

    const float4* c4 = (const float4*)(cls + (size_t)b * NPI);
    const int f0 = t32 * F4PB, fend = f0 + F4PB;

    for (int f = f0 + tid; f < fend; f += 1024) {
        float4 v = c4[f];
        int cb = (f & 1) * 4;
        int n = f >> 1;
        float vv[4] = {v.x, v.y, v.z, v.w};
        #pragma unroll
        for (int k = 0; k < 4; ++k) {
            float s = vv[k];
            if (s > SCORE_T) {
                int bn = (int)(s * 256.0f); if (bn > 255) bn = 255;
                if (bn >= CUTBIN) {
                    int c = cb + k;
                    int pos = atomicAdd(&lcnt[c], 1);
                    u64 key = score_key(s, n);
                    if (pos < LBUF) buf[c][pos] = key;
                    else {
                        int gp = atomicAdd(&cnt_g[b * 8 + c], 1);
                        if (gp < CAP) cand[(size_t)(b * 8 + c) * CAP + gp] = key;
                    }
                }
            }
        }
    }
    __syncthreads();
    if (tid < 8) {
        int m = lcnt[tid]; if (m > LBUF) m = LBUF;
        gbase[tid] = atomicAdd(&cnt_g[b * 8 + tid], m);
    }
    __syncthreads();
    for (int c = 0; c < 8; ++c) {
        int m = lcnt[c]; if (m > LBUF) m = LBUF;
        int gb = gbase[c];
        for (int i = tid; i < m; i += 1024) {
            int gp = gb + i;
            if (gp < CAP) cand[(size_t)(b * 8 + c) * CAP + gp] = buf[c][i];
        }
    }
}

// ---------------- N: fused sort + 512-matrix greedy ------------------------
__global__ __launch_bounds__(NT) void nms_fused(
    const float* __restrict__ boxes, const float* __restrict__ cls,
    const u64* __restrict__ cand, const int* __restrict__ cnt_g,
    int* __restrict__ sel_idx, float* __restrict__ sel_score)
{
    const int bc = blockIdx.x;
    const int b = bc >> 3, c = bc & 7;
    const int tid = threadIdx.x;
    const int lane = tid & 63, widx = tid >> 6;
    const float4* bx4 = (const float4*)(boxes + (size_t)b * NN * 4);
    const float* sr = cls + (size_t)b * NN * NC + c;   // fallback only
    const u64* g = cand + (size_t)bc * CAP;
    int* si = sel_idx + bc * MAX_DET;
    float* ss = sel_score + bc * MAX_DET;

    __shared__ u64 keys[CAP];                          // 8 KB
    __shared__ __align__(16) char regA[32768];         // Mword | {bm, rv, ri}
    __shared__ __align__(16) char regB[14336];         // cbig* | continuation*
    __shared__ u64 accs_s[8];
    __shared__ u64 accmask_s[2];
    __shared__ float4 abox[MAX_DET];
    __shared__ float aarea[MAX_DET];
    __shared__ float sboxsh[5];

    u64 (*Mword)[BIGM] = (u64(*)[BIGM])regA;           // [8][512]
    unsigned* bm = (unsigned*)regA;                    // fallback bitmask (6252B)
    float* rv = (float*)(regA + 6256);
    int*   ri = (int*)(regA + 8304);
    float4* cbig   = (float4*)regB;                    // [512] 8KB
    float* careabig = (float*)(regB + 8192);
    int*   cidxbig  = (int*)(regB + 10240);
    float* csbig    = (float*)(regB + 12288);
    float4 (*cbox2)[CHUNK] = (float4(*)[CHUNK])regB;   // continuation alias
    float*  carea2 = (float*)(regB + 4096);            // [2][128]
    int*    cidx2  = (int*)(regB + 5120);
    float*  cscore2= (float*)(regB + 6144);
    unsigned (*M32)[CHUNK] = (unsigned(*)[CHUNK])(regB + 7168);
    unsigned (*presup4)[CHUNK] = (unsigned(*)[CHUNK])(regB + 9216);

    const int cnt = cnt_g[bc];
    const bool full_fb = (cnt > CAP);
    const int inSet = cnt < CAP ? cnt : CAP;

    int n_acc = 0;
    if (!full_fb) {
        // ===== hybrid register/LDS bitonic sort, descending =====
        const int p0 = widx * 128 + lane, p1 = p0 + 64;
        u64 v0 = (p0 < cnt) ? g[p0] : 0ull;
        u64 v1 = (p1 < cnt) ? g[p1] : 0ull;
        #pragma unroll
        for (int k = 2; k <= 128; k <<= 1) {
            #pragma unroll
            for (int j = k >> 1; j > 0; j >>= 1) {
                if (j == 64) {
                    bool dir = ((p0 & k) == 0);
                    if ((v0 < v1) == dir) { u64 t = v0; v0 = v1; v1 = t; }
                } else {
                    bool lower = ((lane & j) == 0);
                    bool dir0 = ((p0 & k) == 0);
                    bool dir1 = ((p1 & k) == 0);
                    u64 o0 = shfl_xor_u64(v0, j);
                    u64 mx0 = v0 > o0 ? v0 : o0, mn0 = v0 > o0 ? o0 : v0;
                    v0 = (lower == dir0) ? mx0 : mn0;
                    u64 o1 = shfl_xor_u64(v1, j);
                    u64 mx1 = v1 > o1 ? v1 : o1, mn1 = v1 > o1 ? o1 : v1;
                    v1 = (lower == dir1) ? mx1 : mn1;
                }
            }
        }
        for (int k = 256; k <= CAP; k <<= 1) {
            keys[p0] = v0; keys[p1] = v1;
            __syncthreads();
            for (int j = k >> 1; j >= 128; j >>= 1) {
                int p = tid;
                int i = 2 * p - (p & (j - 1));
                int ix = i + j;
                bool dir = ((i & k) == 0);
                u64 a = keys[i], b2 = keys[ix];
                if ((a < b2) == dir) { keys[i] = b2; keys[ix] = a; }
                __syncthreads();
            }
            v0 = keys[p0]; v1 = keys[p1];
            {
                bool dir = ((p0 & k) == 0);
                if ((v0 < v1) == dir) { u64 t = v0; v0 = v1; v1 = t; }
            }
            #pragma unroll
            for (int j = 32; j > 0; j >>= 1) {
                bool lower = ((lane & j) == 0);
                bool dir = ((p0 & k) == 0);
                u64 o0 = shfl_xor_u64(v0, j);
                u64 mx0 = v0 > o0 ? v0 : o0, mn0 = v0 > o0 ? o0 : v0;
                v0 = (lower == dir) ? mx0 : mn0;
                u64 o1 = shfl_xor_u64(v1, j);
                u64 mx1 = v1 > o1 ? v1 : o1, mn1 = v1 > o1 ? o1 : v1;
                v1 = (lower == dir) ? mx1 : mn1;
            }
            __syncthreads();
        }
        keys[p0] = v0; keys[p1] = v1;
        __syncthreads();

        // ===== stage top-512 candidates =====
        const int stage = inSet < BIGM ? inSet : BIGM;
        if (tid < stage) {
            u64 key = keys[tid];
            int idx = (int)(~(unsigned)key);
            unsigned u = (unsigned)(key >> 32);
            unsigned uo = (u & 0x80000000u) ? (u ^ 0x80000000u) : (~u);
            float4 bb = bx4[idx];
            cbig[tid] = bb;
            careabig[tid] = __fmul_rn(__fsub_rn(bb.z, bb.x), __fsub_rn(bb.w, bb.y));
            cidxbig[tid] = idx; csbig[tid] = __uint_as_float(uo);
        }
        __syncthreads();

        // ===== single-phase 512x512 lower-triangle matrix =====
        {
            const int r = tid;
            const int jmax = (widx + 1) << 6;          // wave-uniform bound
            float4 B = cbig[r < stage ? r : 0];
            float  Ba = careabig[r < stage ? r : 0];
            (void)Ba;
            u64 bits = 0;
            for (int j = 0; j < jmax; ++j) {
                if (j < r && r < stage) {
                    float4 A = cbig[j];                // wave-broadcast
                    if (iou_gt(A.x, A.y, A.z, A.w, careabig[j],
                               B.x, B.y, B.z, B.w))
                        bits |= 1ull << (j & 63);
                }
                if ((j & 63) == 63) { Mword[j >> 6][r] = bits; bits = 0; }
            }
        }
        __syncthreads();

        // ===== single-pass resolve (wave 0) =====
        if (tid < 64) {
            u64 acc[8];
            #pragma unroll
            for (int gg = 0; gg < 8; ++gg) acc[gg] = 0ull;
            const int stage = inSet < BIGM ? inSet : BIGM;
            for (int gg = 0; gg < 8; ++gg) {
                int i = gg * 64 + lane;
                unsigned pe = (i < stage) ? 0u : 1u;
                u64 mg = 0;
                if (i < stage) {
                    mg = Mword[gg][i];
                    for (int h = 0; h < gg; ++h)
                        if (Mword[h][i] & acc[h]) pe = 1;
                }
                u64 rem = ~__ballot(pe != 0);
                u64 accw = 0;
                while (rem) {
                    int l = __builtin_ctzll(rem);
                    accw |= 1ull << l;
                    rem &= ~(1ull << l);
                    u64 supm = __ballot(((mg >> l) & 1ull) != 0);
                    rem &= ~supm;
                }
                acc[gg] = accw;
            }
            if (lane == 0) {
                #pragma unroll
                for (int gg = 0; gg < 8; ++gg) accs_s[gg] = acc[gg];
            }
        }
        __syncthreads();

        // ===== rank + write accepted (cap 300) =====
        {
            int total_acc = 0;
            #pragma unroll
            for (int gg = 0; gg < 8; ++gg) total_acc += __popcll(accs_s[gg]);
            int gg = widx, o = 0; // recompute per-thread below
            gg = tid >> 6; o = tid & 63;
            u64 aw = accs_s[gg];
            if ((aw >> o) & 1ull) {
                int rank = 0;
                for (int h = 0; h < gg; ++h) rank += __popcll(accs_s[h]);
                rank += __popcll(aw & ((1ull << o) - 1ull));
                if (rank < MAX_DET) {
                    abox[rank] = cbig[tid]; aarea[rank] = careabig[tid];
                    si[rank] = cidxbig[tid]; ss[rank] = csbig[tid];
                }
            }
            n_acc = total_acc < MAX_DET ? total_acc : MAX_DET;
        }
        __syncthreads();   // abox visible; regB free for continuation

        // ===== rare continuation: chunked greedy for candidates 512.. =====
        int base = BIGM, cur = 0;
        if (n_acc < MAX_DET && base < inSet) {
            if (tid < CHUNK && base + tid < inSet) {
                u64 key = keys[base + tid];
                int idx = (int)(~(unsigned)key);
                unsigned u = (unsigned)(key >> 32);
                unsigned uo = (u & 0x80000000u) ? (u ^ 0x80000000u) : (~u);
                float4 bb = bx4[idx];
                cbox2[0][tid] = bb;
                carea2[0 * CHUNK + tid] = __fmul_rn(__fsub_rn(bb.z, bb.x), __fsub_rn(bb.w, bb.y));
                cidx2[0 * CHUNK + tid] = idx; cscore2[0 * CHUNK + tid] = __uint_as_float(uo);
            }
            __syncthreads();
            while (n_acc < MAX_DET && base < inSet) {
                int m = inSet - base; if (m > CHUNK) m = CHUNK;
                {
                    int i = tid & (CHUNK - 1);
                    int q = tid >> 7;
                    if (i < m) {
                        float4 B = cbox2[cur][i];
                        unsigned p = 0;
                        for (int t = q; t < n_acc; t += 4) {
                            float4 A = abox[t];
                            if (iou_gt(A.x, A.y, A.z, A.w, aarea[t],
                                       B.x, B.y, B.z, B.w)) { p = 1; break; }
                        }
                        presup4[q][i] = p;
                        unsigned bits = 0;
                        int j0 = q * 32;
                        int jend = i - j0; if (jend > 32) jend = 32;
                        for (int jj = 0; jj < jend; ++jj) {
                            int j = j0 + jj;
                            float4 A = cbox2[cur][j];
                            if (iou_gt(A.x, A.y, A.z, A.w, carea2[cur * CHUNK + j],
                                       B.x, B.y, B.z, B.w))
                                bits |= 1u << jj;
                        }
                        M32[q][i] = bits;
                    }
                }
                __syncthreads();
                int nbase = base + m;
                if (tid < 64) {
                    u64 a0 = 0, a1 = 0;
                    int ngroups = (m + 63) >> 6;
                    for (int gg = 0; gg < ngroups; ++gg) {
                        int i = gg * 64 + lane;
                        unsigned pe = 1; u64 mg = 0;
                        if (i < m) {
                            pe = presup4[0][i] | presup4[1][i] | presup4[2][i] | presup4[3][i];
                            mg = (u64)M32[2 * gg][i] | ((u64)M32[2 * gg + 1][i] << 32);
                            if (gg > 0) {
                                u64 w0 = (u64)M32[0][i] | ((u64)M32[1][i] << 32);
                                if (w0 & a0) pe = 1;
                            }
                        }
                        u64 rem = ~__ballot(pe != 0);
                        u64 accw = 0;
                        while (rem) {
                            int l = __builtin_ctzll(rem);
                            accw |= 1ull << l;
                            rem &= ~(1ull << l);
                            u64 supm = __ballot(((mg >> l) & 1ull) != 0);
                            rem &= ~supm;
                        }
                        if (gg == 0) a0 = accw; else a1 = accw;
                    }
                    if (lane == 0) { accmask_s[0] = a0; accmask_s[1] = a1; }
                } else if (nbase < inSet) {
                    int w = tid - 64;
                    if (w < CHUNK && nbase + w < inSet) {
                        u64 key = keys[nbase + w];
                        int idx = (int)(~(unsigned)key);
                        unsigned u = (unsigned)(key >> 32);
                        unsigned uo = (u & 0x80000000u) ? (u ^ 0x80000000u) : (~u);
                        float4 bb = bx4[idx];
                        cbox2[cur ^ 1][w] = bb;
                        carea2[(cur ^ 1) * CHUNK + w] = __fmul_rn(__fsub_rn(bb.z, bb.x), __fsub_rn(bb.w, bb.y));
                        cidx2[(cur ^ 1) * CHUNK + w] = idx;
                        cscore2[(cur ^ 1) * CHUNK + w] = __uint_as_float(uo);
                    }
                }
                __syncthreads();
                u64 a0 = accmask_s[0], a1 = accmask_s[1];
                int add = __popcll(a0) + __popcll(a1);
                if (tid < m) {
                    int gg = tid >> 6, o = tid & 63;
                    u64 aw = (gg == 0) ? a0 : a1;
                    if ((aw >> o) & 1ull) {
                        int rank = (gg > 0) ? __popcll(a0) : 0;
                        rank += __popcll(aw & ((1ull << o) - 1ull));
                        int pos = n_acc + rank;
                        if (pos < MAX_DET) {
                            abox[pos] = cbox2[cur][tid]; aarea[pos] = carea2[cur * CHUNK + tid];
                            si[pos] = cidx2[cur * CHUNK + tid]; ss[pos] = cscore2[cur * CHUNK + tid];
                        }
                    }
                }
                n_acc += add; if (n_acc > MAX_DET) n_acc = MAX_DET;
                base = nbase; cur ^= 1;
                __syncthreads();
            }
        }
    }

    const bool part_fb = (!full_fb) && (n_acc < MAX_DET);

    if (full_fb || part_fb) {
        // ======== exact fallback: bitmask argmax loop (aliases regA) ========
        const int BMW = (NN + 31) / 32;
        for (int i = tid; i < BMW; i += NT) bm[i] = 0u;
        __syncthreads();
        if (full_fb) {
            n_acc = 0;
        } else {
            for (int n = tid; n < NN; n += NT) {
                float4 bbn = bx4[n];
                int s = 0;
                for (int t = 0; t < n_acc; ++t) {
                    float4 A = abox[t];
                    if (iou_gt(A.x, A.y, A.z, A.w, aarea[t],
                               bbn.x, bbn.y, bbn.z, bbn.w)) s = 1;
                }
                if (s) atomicOr(&bm[n >> 5], 1u << (n & 31));
            }
        }
        __syncthreads();

        for (int k = n_acc; k < MAX_DET; ++k) {
            float bv = neg_inf(); int bi = 0x7fffffff;
            for (int n = tid; n < NN; n += NT) {
                if (!((bm[n >> 5] >> (n & 31)) & 1u)) {
                    float v = sr[(size_t)n * NC];
                    if (v > SCORE_T && v > bv) { bv = v; bi = n; }
                }
            }
            rv[tid] = bv; ri[tid] = bi;
            __syncthreads();
            for (int s = NT / 2; s > 0; s >>= 1) {
                if (tid < s) {
                    float ov = rv[tid + s]; int oi = ri[tid + s];
                    if (ov > rv[tid] || (ov == rv[tid] && oi < ri[tid])) { rv[tid] = ov; ri[tid] = oi; }
                }
                __syncthreads();
            }
            float mval = rv[0]; int midx = ri[0];
            if (mval == neg_inf()) {
                for (int kk = k + tid; kk < MAX_DET; kk += NT) { si[kk] = 0; ss[kk] = neg_inf(); }
                break;
            }
            if (tid == 0) {
                si[k] = midx; ss[k] = mval;
                float4 sb = bx4[midx];
                sboxsh[0] = sb.x; sboxsh[1] = sb.y; sboxsh[2] = sb.z; sboxsh[3] = sb.w;
                sboxsh[4] = __fmul_rn(__fsub_rn(sb.z, sb.x), __fsub_rn(sb.w, sb.y));
            }
            __syncthreads();
            float ax1 = sboxsh[0], ay1 = sboxsh[1], ax2 = sboxsh[2], ay2 = sboxsh[3];
            float area_a = sboxsh[4];
            for (int n = tid; n < NN; n += NT) {
                float4 bbn = bx4[n];
                if (iou_gt(ax1, ay1, ax2, ay2, area_a,
                           bbn.x, bbn.y, bbn.z, bbn.w))
                    atomicOr(&bm[n >> 5], 1u << (n & 31));
            }
            __syncthreads();
        }
    } else {
        for (int kk = n_acc + tid; kk < MAX_DET; kk += NT) { si[kk] = 0; ss[kk] = neg_inf(); }
    }
}

// ---------------- T: top-300 via 8-way merge of sorted class lists --------
__global__ __launch_bounds__(1024) void topk_kernel(
    const float* __restrict__ boxes, const float* __restrict__ other,
    const int* __restrict__ sel_idx, const float* __restrict__ sel_score,
    float* __restrict__ out)
{
    const int b = blockIdx.x;
    const int tid = threadIdx.x;
    __shared__ u64 keys[4096];

    for (int i = tid; i < 4096; i += 1024) {
        int c = i >> 9, o = i & 511;
        u64 key = 0ull;
        if (o < MAX_DET) {
            int m = c * MAX_DET + o;
            float v = sel_score[b * NC * MAX_DET + m];
            unsigned u = __float_as_uint(v);
            u ^= (u & 0x80000000u) ? 0xFFFFFFFFu : 0x80000000u;
            key = ((u64)u << 32) | (unsigned)(~(unsigned)m);
        }
        keys[i] = key;
    }

    for (int seg = 1024; seg <= 4096; seg <<= 1) {
        int half = seg >> 1;
        __syncthreads();
        {
            int p = tid;
            int s = p / (half >> 1), t = p % (half >> 1);
            int i0 = s * seg + half + t;
            int i1 = s * seg + seg - 1 - t;
            u64 a = keys[i0]; keys[i0] = keys[i1]; keys[i1] = a;
        }
        __syncthreads();
        for (int j = half; j > 0; j >>= 1) {
            for (int p = tid; p < 2048; p += 1024) {
                int i = 2 * p - (p & (j - 1));
                int ix = i + j;
                u64 a = keys[i], bq = keys[ix];
                if (a < bq) { keys[i] = bq; keys[ix] = a; }
            }
            if (j >= 128) __syncthreads(); else __threadfence_block();
        }
    }
    __syncthreads();

    const float4* bx4 = (const float4*)(boxes + (size_t)b * NN * 4);
    const float*  ot  = other + (size_t)b * NN * ND;
    float* ob = out;
    float* os = out + NB * MAX_DET * 4;
    float* ol = os + NB * MAX_DET;
    float* oo = ol + NB * MAX_DET;

    for (int k = tid; k < MAX_DET; k += 1024) {
        u64 key = keys[k];
        unsigned u = (unsigned)(key >> 32);
        unsigned uo = (u & 0x80000000u) ? (u ^ 0x80000000u) : (u ^ 0xFFFFFFFFu);
        float score = __uint_as_float(uo);
        bool valid = isfinite(score);
        float b0=-1.f,b1=-1.f,b2=-1.f,b3=-1.f,scv=-1.f,lab=-1.f,o0=-1.f,o1=-1.f;
        if (valid) {
            int m = (int)(~(unsigned)key);
            int c = m / MAX_DET, slot = m - c * MAX_DET;
            int n = sel_idx[(b * NC + c) * MAX_DET + slot];
            float4 bb = bx4[n];
            b0 = bb.x; b1 = bb.y; b2 = bb.z; b3 = bb.w;
            scv = score; lab = (float)c;
            o0 = ot[n * ND + 0]; o1 = ot[n * ND + 1];
        }
        int base = b * MAX_DET + k;
        ob[base * 4 + 0] = b0; ob[base * 4 + 1] = b1;
        ob[base * 4 + 2] = b2; ob[base * 4 + 3] = b3;
        os[base] = scv; ol[base] = lab;
        oo[base * 2 + 0] = o0; oo[base * 2 + 1] = o1;
    }
}

extern "C" void kernel_launch(void* const* d_in, const int* in_sizes, int n_in,
                              void* d_out, int out_size, void* d_ws, size_t ws_size,
                              hipStream_t stream) {
    const float* boxes = (const float*)d_in[0];
    const float* cls   = (const float*)d_in[1];
    const float* other = (const float*)d_in[2];
    float* out = (float*)d_out;

    int* cnt_g = (int*)d_ws;
    u64* cand  = (u64*)(cnt_g + NB * NC * 2);
    int* sel_idx = (int*)(cand + (size_t)NB * NC * CAP);
    float* sel_score = (float*)(sel_idx + NB * NC * MAX_DET);

    hipMemsetAsync(cnt_g, 0, NB * NC * sizeof(int), stream);
    compact_kernel<<<NB * CBLK, 1024, 0, stream>>>(cls, cnt_g, cand);
    nms_fused<<<NB * NC, NT, 0, stream>>>(boxes, cls, cand, cnt_g,
                                          sel_idx, sel_score);
    topk_kernel<<<NB, 1024, 0, stream>>>(boxes, other, sel_idx, sel_score, out);
}

// Round 13
// 67.158 us; speedup vs baseline: 1.9123x; 1.9123x over previous
//
#include <hip/hip_runtime.h>
#include <math.h>
#include <stdint.h>

#define NB 16
#define NN 50000
#define NC 8
#define ND 2
#define MAX_DET 300
#define NMS_T 0.5f
#define SCORE_T 0.05f
#define CAP 1024
#define CUTBIN 252        // s >= 0.984375 ; E[cnt]=781 +- 28
#define LBUF 128          // per-(class,tile) segment; E=24.4, +20 sigma
#define NTILE32 32
#define CHUNK 128
#define NT 512
#define NPI (NN * NC)
#define F4PB (NPI / 4 / NTILE32)   // 3125 float4 per compact block

typedef unsigned long long u64;

__device__ __forceinline__ float neg_inf() { return -__builtin_inff(); }

// Bit-exact IoU > 0.5, division-free (R11-validated, absmax 0).
__device__ __forceinline__ bool iou_gt(float ax1, float ay1, float ax2, float ay2,
                                       float area_a,
                                       float bx1, float by1, float bx2, float by2) {
    float x1 = fmaxf(ax1, bx1), y1 = fmaxf(ay1, by1);
    float x2 = fminf(ax2, bx2), y2 = fminf(ay2, by2);
    float inter = __fmul_rn(fmaxf(__fsub_rn(x2, x1), 0.0f),
                            fmaxf(__fsub_rn(y2, y1), 0.0f));
    float area_b = __fmul_rn(__fsub_rn(bx2, bx1), __fsub_rn(by2, by1));
    float uni = __fsub_rn(__fadd_rn(area_a, area_b), inter);
    return inter > __fmul_rn(0.5f, fmaxf(uni, 1e-8f));
}

__device__ __forceinline__ u64 score_key(float s, int n) {
    unsigned u = __float_as_uint(s);
    u ^= (u & 0x80000000u) ? 0xFFFFFFFFu : 0x80000000u;
    return ((u64)u << 32) | (unsigned)(~(unsigned)n);
}

__device__ __forceinline__ u64 shfl_xor_u64(u64 v, int m) {
    unsigned lo = (unsigned)v, hi = (unsigned)(v >> 32);
    lo = __shfl_xor(lo, m, 64);
    hi = __shfl_xor(hi, m, 64);
    return ((u64)hi << 32) | lo;
}

// ---------------- C: tiled compaction, NO global atomics ------------------
// block = (b, tile). Writes cand[(bc*32+t)*LBUF + i] and tcnt_g[bc*32+t].
__global__ __launch_bounds__(1024) void compact_kernel(
    const float* __restrict__ cls, int* __restrict__ tcnt_g,
    u64* __restrict__ cand)
{
    const int b = blockIdx.x >> 5, t32 = blockIdx.x & 31;
    const int tid = threadIdx.x;
    __shared__ u64 buf[8][LBUF];
    __shared__ int lcnt[8];
    if (tid < 8) lcnt[tid] = 0;
    __syncthreads();

    const float4* c4 = (const float4*)(cls + (size_t)b * NPI);
    const int f0 = t32 * F4PB, fend = f0 + F4PB;

    for (int f = f0 + tid; f < fend; f += 1024) {
        float4 v = c4[f];
        int cb = (f & 1) * 4;
        int n = f >> 1;
        float vv[4] = {v.x, v.y, v.z, v.w};
        #pragma unroll
        for (int k = 0; k < 4; ++k) {
            float s = vv[k];
            if (s > SCORE_T) {
                int bn = (int)(s * 256.0f); if (bn > 255) bn = 255;
                if (bn >= CUTBIN) {
                    int c = cb + k;
                    int pos = atomicAdd(&lcnt[c], 1);   // LDS only
                    if (pos < LBUF) buf[c][pos] = score_key(s, n);
                    // overflow: dropped here; tcnt>LBUF forces exact fallback
                }
            }
        }
    }
    __syncthreads();
    // flat dump: 1024 threads cover 8*128 slots in one shot
    {
        int c = tid >> 7, i = tid & (LBUF - 1);
        int m = lcnt[c];
        if (i < (m < LBUF ? m : LBUF))
            cand[(size_t)(((b * 8 + c) * NTILE32) + t32) * LBUF + i] = buf[c][i];
        if (i == 0) tcnt_g[(b * 8 + c) * NTILE32 + t32] = m;   // RAW count
    }
}

// ---------------- N: fused gather + sort + chunked greedy ------------------
__global__ __launch_bounds__(NT) void nms_fused(
    const float* __restrict__ boxes, const float* __restrict__ cls,
    const u64* __restrict__ cand, const int* __restrict__ tcnt_g,
    int* __restrict__ sel_idx, float* __restrict__ sel_score)
{
    const int bc = blockIdx.x;
    const int b = bc >> 3, c = bc & 7;
    const int tid = threadIdx.x;
    const int lane = tid & 63, widx = tid >> 6;
    const float4* bx4 = (const float4*)(boxes + (size_t)b * NN * 4);
    const float* sr = cls + (size_t)b * NN * NC + c;   // fallback only
    int* si = sel_idx + bc * MAX_DET;
    float* ss = sel_score + bc * MAX_DET;

    __shared__ u64 keys[CAP];
    __shared__ int tcnt_s[NTILE32], toff_s[NTILE32];
    __shared__ int sh_total, sh_ovf;
    __shared__ float4 cbox2[2][CHUNK];
    __shared__ float  carea2[2][CHUNK];
    __shared__ int    cidx2[2][CHUNK];
    __shared__ float  cscore2[2][CHUNK];
    __shared__ unsigned M32[4][CHUNK];
    __shared__ unsigned presup4[4][CHUNK];
    __shared__ u64 accmask_s[2];
    __shared__ float4 abox[MAX_DET];
    __shared__ float aarea[MAX_DET];
    __shared__ unsigned bm[(NN + 31) / 32];
    __shared__ float rv[NT];
    __shared__ int   ri[NT];
    __shared__ float sboxsh[5];

    // ---- tile-count scan (wave 0, shfl) ----
    if (tid < 64) {
        int v = (lane < NTILE32) ? tcnt_g[bc * NTILE32 + lane] : 0;
        int incl = v;
        #pragma unroll
        for (int d = 1; d < 32; d <<= 1) {
            int o = __shfl_up(incl, d, 64);
            if (lane >= d) incl += o;
        }
        if (lane < NTILE32) { tcnt_s[lane] = v; toff_s[lane] = incl - v; }
        u64 ov = __ballot(lane < NTILE32 && v > LBUF);
        if (lane == 31) { sh_total = incl; sh_ovf = (ov != 0); }
    }
    __syncthreads();
    const int cnt = sh_total;
    const bool full_fb = sh_ovf || (cnt > CAP);
    const int inSet = cnt < CAP ? cnt : CAP;

    int n_acc = 0;
    if (!full_fb) {
        // ---- zero + flat gather into keys (no dependent chains) ----
        for (int i = tid; i < CAP; i += NT) keys[i] = 0ull;
        __syncthreads();
        for (int s = tid; s < NTILE32 * LBUF; s += NT) {
            int t = s >> 7, i = s & (LBUF - 1);
            if (i < tcnt_s[t])
                keys[toff_s[t] + i] = cand[(size_t)(bc * NTILE32 + t) * LBUF + i];
        }
        __syncthreads();

        // ===== hybrid register/LDS bitonic sort, descending =====
        const int p0 = widx * 128 + lane, p1 = p0 + 64;
        u64 v0 = keys[p0];
        u64 v1 = keys[p1];
        #pragma unroll
        for (int k = 2; k <= 128; k <<= 1) {
            #pragma unroll
            for (int j = k >> 1; j > 0; j >>= 1) {
                if (j == 64) {
                    bool dir = ((p0 & k) == 0);
                    if ((v0 < v1) == dir) { u64 t = v0; v0 = v1; v1 = t; }
                } else {
                    bool lower = ((lane & j) == 0);
                    bool dir0 = ((p0 & k) == 0);
                    bool dir1 = ((p1 & k) == 0);   // differs at k=64
                    u64 o0 = shfl_xor_u64(v0, j);
                    u64 mx0 = v0 > o0 ? v0 : o0, mn0 = v0 > o0 ? o0 : v0;
                    v0 = (lower == dir0) ? mx0 : mn0;
                    u64 o1 = shfl_xor_u64(v1, j);
                    u64 mx1 = v1 > o1 ? v1 : o1, mn1 = v1 > o1 ? o1 : v1;
                    v1 = (lower == dir1) ? mx1 : mn1;
                }
            }
        }
        __syncthreads();   // gather reads done before keys overwrite
        for (int k = 256; k <= CAP; k <<= 1) {
            keys[p0] = v0; keys[p1] = v1;
            __syncthreads();
            for (int j = k >> 1; j >= 128; j >>= 1) {
                int p = tid;
                int i = 2 * p - (p & (j - 1));
                int ix = i + j;
                bool dir = ((i & k) == 0);
                u64 a = keys[i], b2 = keys[ix];
                if ((a < b2) == dir) { keys[i] = b2; keys[ix] = a; }
                __syncthreads();
            }
            v0 = keys[p0]; v1 = keys[p1];
            {
                bool dir = ((p0 & k) == 0);
                if ((v0 < v1) == dir) { u64 t = v0; v0 = v1; v1 = t; }
            }
            #pragma unroll
            for (int j = 32; j > 0; j >>= 1) {
                bool lower = ((lane & j) == 0);
                bool dir = ((p0 & k) == 0);
                u64 o0 = shfl_xor_u64(v0, j);
                u64 mx0 = v0 > o0 ? v0 : o0, mn0 = v0 > o0 ? o0 : v0;
                v0 = (lower == dir) ? mx0 : mn0;
                u64 o1 = shfl_xor_u64(v1, j);
                u64 mx1 = v1 > o1 ? v1 : o1, mn1 = v1 > o1 ? o1 : v1;
                v1 = (lower == dir) ? mx1 : mn1;
            }
            __syncthreads();
        }
        keys[p0] = v0; keys[p1] = v1;
        __syncthreads();

        // ===== chunked greedy accept (pipelined gather) =====
        if (tid < CHUNK && tid < inSet) {
            u64 key = keys[tid];
            int idx = (int)(~(unsigned)key);
            unsigned u = (unsigned)(key >> 32);
            unsigned uo = (u & 0x80000000u) ? (u ^ 0x80000000u) : (~u);
            float4 bb = bx4[idx];
            cbox2[0][tid] = bb;
            carea2[0][tid] = __fmul_rn(__fsub_rn(bb.z, bb.x), __fsub_rn(bb.w, bb.y));
            cidx2[0][tid] = idx; cscore2[0][tid] = __uint_as_float(uo);
        }
        __syncthreads();

        int base = 0, cur = 0;
        while (n_acc < MAX_DET && base < inSet) {
            int m = inSet - base; if (m > CHUNK) m = CHUNK;

            {
                int i = tid & (CHUNK - 1);
                int q = tid >> 7;
                if (i < m) {
                    float4 B = cbox2[cur][i];
                    // presup vs accepted: batched x4 (breaks LDS chain)
                    unsigned p = 0;
                    int t = q;
                    for (; t + 12 < n_acc; t += 16) {
                        float4 A0 = abox[t];      float r0 = aarea[t];
                        float4 A1 = abox[t + 4];  float r1 = aarea[t + 4];
                        float4 A2 = abox[t + 8];  float r2 = aarea[t + 8];
                        float4 A3 = abox[t + 12]; float r3 = aarea[t + 12];
                        bool s0 = iou_gt(A0.x,A0.y,A0.z,A0.w,r0,B.x,B.y,B.z,B.w);
                        bool s1 = iou_gt(A1.x,A1.y,A1.z,A1.w,r1,B.x,B.y,B.z,B.w);
                        bool s2 = iou_gt(A2.x,A2.y,A2.z,A2.w,r2,B.x,B.y,B.z,B.w);
                        bool s3 = iou_gt(A3.x,A3.y,A3.z,A3.w,r3,B.x,B.y,B.z,B.w);
                        if (s0 || s1 || s2 || s3) { p = 1; break; }
                    }
                    if (!p) {
                        for (; t < n_acc; t += 4) {
                            float4 A = abox[t];
                            if (iou_gt(A.x,A.y,A.z,A.w,aarea[t],
                                       B.x,B.y,B.z,B.w)) { p = 1; break; }
                        }
                    }
                    presup4[q][i] = p;
                    // lower-triangle matrix: batched x4 loads
                    unsigned bits = 0;
                    int j0 = q * 32;
                    int jend = i - j0; if (jend > 32) jend = 32;
                    int jj = 0;
                    for (; jj + 3 < jend; jj += 4) {
                        int j = j0 + jj;
                        float4 A0 = cbox2[cur][j];     float r0 = carea2[cur][j];
                        float4 A1 = cbox2[cur][j + 1]; float r1 = carea2[cur][j + 1];
                        float4 A2 = cbox2[cur][j + 2]; float r2 = carea2[cur][j + 2];
                        float4 A3 = cbox2[cur][j + 3]; float r3 = carea2[cur][j + 3];
                        if (iou_gt(A0.x,A0.y,A0.z,A0.w,r0,B.x,B.y,B.z,B.w)) bits |= 1u << jj;
                        if (iou_gt(A1.x,A1.y,A1.z,A1.w,r1,B.x,B.y,B.z,B.w)) bits |= 1u << (jj+1);
                        if (iou_gt(A2.x,A2.y,A2.z,A2.w,r2,B.x,B.y,B.z,B.w)) bits |= 1u << (jj+2);
                        if (iou_gt(A3.x,A3.y,A3.z,A3.w,r3,B.x,B.y,B.z,B.w)) bits |= 1u << (jj+3);
                    }
                    for (; jj < jend; ++jj) {
                        int j = j0 + jj;
                        float4 A = cbox2[cur][j];
                        if (iou_gt(A.x,A.y,A.z,A.w,carea2[cur][j],
                                   B.x,B.y,B.z,B.w)) bits |= 1u << jj;
                    }
                    M32[q][i] = bits;
                }
            }
            __syncthreads();

            int nbase = base + m;
            if (tid < 64) {
                // wave 0: ballot-driven greedy resolve
                u64 a0 = 0, a1 = 0;
                int ngroups = (m + 63) >> 6;
                for (int gg = 0; gg < ngroups; ++gg) {
                    int i = gg * 64 + lane;
                    unsigned pe = 1; u64 mg = 0;
                    if (i < m) {
                        pe = presup4[0][i] | presup4[1][i] | presup4[2][i] | presup4[3][i];
                        mg = (u64)M32[2 * gg][i] | ((u64)M32[2 * gg + 1][i] << 32);
                        if (gg > 0) {
                            u64 w0 = (u64)M32[0][i] | ((u64)M32[1][i] << 32);
                            if (w0 & a0) pe = 1;
                        }
                    }
                    u64 rem = ~__ballot(pe != 0);
                    u64 accw = 0;
                    while (rem) {
                        int l = __builtin_ctzll(rem);
                        accw |= 1ull << l;
                        rem &= ~(1ull << l);
                        u64 supm = __ballot(((mg >> l) & 1ull) != 0);
                        rem &= ~supm;
                    }
                    if (gg == 0) a0 = accw; else a1 = accw;
                }
                if (lane == 0) { accmask_s[0] = a0; accmask_s[1] = a1; }
            } else if (nbase < inSet) {
                // waves 1-7: gather next chunk under resolve
                int w = tid - 64;
                if (w < CHUNK && nbase + w < inSet) {
                    u64 key = keys[nbase + w];
                    int idx = (int)(~(unsigned)key);
                    unsigned u = (unsigned)(key >> 32);
                    unsigned uo = (u & 0x80000000u) ? (u ^ 0x80000000u) : (~u);
                    float4 bb = bx4[idx];
                    cbox2[cur ^ 1][w] = bb;
                    carea2[cur ^ 1][w] = __fmul_rn(__fsub_rn(bb.z, bb.x), __fsub_rn(bb.w, bb.y));
                    cidx2[cur ^ 1][w] = idx; cscore2[cur ^ 1][w] = __uint_as_float(uo);
                }
            }
            __syncthreads();

            u64 a0 = accmask_s[0], a1 = accmask_s[1];
            int add = __popcll(a0) + __popcll(a1);
            if (tid < m) {
                int gg = tid >> 6, o = tid & 63;
                u64 aw = (gg == 0) ? a0 : a1;
                if ((aw >> o) & 1ull) {
                    int rank = (gg > 0) ? __popcll(a0) : 0;
                    rank += __popcll(aw & ((1ull << o) - 1ull));
                    int pos = n_acc + rank;
                    if (pos < MAX_DET) {
                        abox[pos] = cbox2[cur][tid]; aarea[pos] = carea2[cur][tid];
                        si[pos] = cidx2[cur][tid]; ss[pos] = cscore2[cur][tid];
                    }
                }
            }
            n_acc += add; if (n_acc > MAX_DET) n_acc = MAX_DET;
            base = nbase; cur ^= 1;
            __syncthreads();
        }
    }

    const bool part_fb = (!full_fb) && (n_acc < MAX_DET);

    if (full_fb || part_fb) {
        // ======== exact fallback: bitmask argmax loop ========
        const int BMW = (NN + 31) / 32;
        for (int i = tid; i < BMW; i += NT) bm[i] = 0u;
        __syncthreads();
        if (full_fb) {
            n_acc = 0;
        } else {
            for (int n = tid; n < NN; n += NT) {
                float4 bbn = bx4[n];
                int s = 0;
                for (int t = 0; t < n_acc; ++t) {
                    float4 A = abox[t];
                    if (iou_gt(A.x, A.y, A.z, A.w, aarea[t],
                               bbn.x, bbn.y, bbn.z, bbn.w)) s = 1;
                }
                if (s) atomicOr(&bm[n >> 5], 1u << (n & 31));
            }
        }
        __syncthreads();

        for (int k = n_acc; k < MAX_DET; ++k) {
            float bv = neg_inf(); int bi = 0x7fffffff;
            for (int n = tid; n < NN; n += NT) {
                if (!((bm[n >> 5] >> (n & 31)) & 1u)) {
                    float v = sr[(size_t)n * NC];
                    if (v > SCORE_T && v > bv) { bv = v; bi = n; }
                }
            }
            rv[tid] = bv; ri[tid] = bi;
            __syncthreads();
            for (int s = NT / 2; s > 0; s >>= 1) {
                if (tid < s) {
                    float ov = rv[tid + s]; int oi = ri[tid + s];
                    if (ov > rv[tid] || (ov == rv[tid] && oi < ri[tid])) { rv[tid] = ov; ri[tid] = oi; }
                }
                __syncthreads();
            }
            float mval = rv[0]; int midx = ri[0];
            if (mval == neg_inf()) {
                for (int kk = k + tid; kk < MAX_DET; kk += NT) { si[kk] = 0; ss[kk] = neg_inf(); }
                break;
            }
            if (tid == 0) {
                si[k] = midx; ss[k] = mval;
                float4 sb = bx4[midx];
                sboxsh[0] = sb.x; sboxsh[1] = sb.y; sboxsh[2] = sb.z; sboxsh[3] = sb.w;
                sboxsh[4] = __fmul_rn(__fsub_rn(sb.z, sb.x), __fsub_rn(sb.w, sb.y));
            }
            __syncthreads();
            float ax1 = sboxsh[0], ay1 = sboxsh[1], ax2 = sboxsh[2], ay2 = sboxsh[3];
            float area_a = sboxsh[4];
            for (int n = tid; n < NN; n += NT) {
                float4 bbn = bx4[n];
                if (iou_gt(ax1, ay1, ax2, ay2, area_a,
                           bbn.x, bbn.y, bbn.z, bbn.w))
                    atomicOr(&bm[n >> 5], 1u << (n & 31));
            }
            __syncthreads();
        }
    } else {
        for (int kk = n_acc + tid; kk < MAX_DET; kk += NT) { si[kk] = 0; ss[kk] = neg_inf(); }
    }
}

// ---------------- T: top-300 via 8-way merge of sorted class lists --------
__global__ __launch_bounds__(1024) void topk_kernel(
    const float* __restrict__ boxes, const float* __restrict__ other,
    const int* __restrict__ sel_idx, const float* __restrict__ sel_score,
    float* __restrict__ out)
{
    const int b = blockIdx.x;
    const int tid = threadIdx.x;
    __shared__ u64 keys[4096];

    for (int i = tid; i < 4096; i += 1024) {
        int c = i >> 9, o = i & 511;
        u64 key = 0ull;
        if (o < MAX_DET) {
            int m = c * MAX_DET + o;
            float v = sel_score[b * NC * MAX_DET + m];
            unsigned u = __float_as_uint(v);
            u ^= (u & 0x80000000u) ? 0xFFFFFFFFu : 0x80000000u;
            key = ((u64)u << 32) | (unsigned)(~(unsigned)m);
        }
        keys[i] = key;
    }

    for (int seg = 1024; seg <= 4096; seg <<= 1) {
        int half = seg >> 1;
        __syncthreads();
        {
            int p = tid;
            int s = p / (half >> 1), t = p % (half >> 1);
            int i0 = s * seg + half + t;
            int i1 = s * seg + seg - 1 - t;
            u64 a = keys[i0]; keys[i0] = keys[i1]; keys[i1] = a;
        }
        __syncthreads();
        for (int j = half; j > 0; j >>= 1) {
            for (int p = tid; p < 2048; p += 1024) {
                int i = 2 * p - (p & (j - 1));
                int ix = i + j;
                u64 a = keys[i], bq = keys[ix];
                if (a < bq) { keys[i] = bq; keys[ix] = a; }
            }
            if (j >= 128) __syncthreads(); else __threadfence_block();
        }
    }
    __syncthreads();

    const float4* bx4 = (const float4*)(boxes + (size_t)b * NN * 4);
    const float*  ot  = other + (size_t)b * NN * ND;
    float* ob = out;
    float* os = out + NB * MAX_DET * 4;
    float* ol = os + NB * MAX_DET;
    float* oo = ol + NB * MAX_DET;

    for (int k = tid; k < MAX_DET; k += 1024) {
        u64 key = keys[k];
        unsigned u = (unsigned)(key >> 32);
        unsigned uo = (u & 0x80000000u) ? (u ^ 0x80000000u) : (u ^ 0xFFFFFFFFu);
        float score = __uint_as_float(uo);
        bool valid = isfinite(score);
        float b0=-1.f,b1=-1.f,b2=-1.f,b3=-1.f,scv=-1.f,lab=-1.f,o0=-1.f,o1=-1.f;
        if (valid) {
            int m = (int)(~(unsigned)key);
            int c = m / MAX_DET, slot = m - c * MAX_DET;
            int n = sel_idx[(b * NC + c) * MAX_DET + slot];
            float4 bb = bx4[n];
            b0 = bb.x; b1 = bb.y; b2 = bb.z; b3 = bb.w;
            scv = score; lab = (float)c;
            o0 = ot[n * ND + 0]; o1 = ot[n * ND + 1];
        }
        int base = b * MAX_DET + k;
        ob[base * 4 + 0] = b0; ob[base * 4 + 1] = b1;
        ob[base * 4 + 2] = b2; ob[base * 4 + 3] = b3;
        os[base] = scv; ol[base] = lab;
        oo[base * 2 + 0] = o0; oo[base * 2 + 1] = o1;
    }
}

extern "C" void kernel_launch(void* const* d_in, const int* in_sizes, int n_in,
                              void* d_out, int out_size, void* d_ws, size_t ws_size,
                              hipStream_t stream) {
    const float* boxes = (const float*)d_in[0];
    const float* cls   = (const float*)d_in[1];
    const float* other = (const float*)d_in[2];
    float* out = (float*)d_out;

    // ws: tcnt[128*32] | cand[128*32*LBUF] u64 | sel_idx | sel_score
    int* tcnt_g = (int*)d_ws;
    u64* cand  = (u64*)(tcnt_g + NB * NC * NTILE32);
    int* sel_idx = (int*)(cand + (size_t)NB * NC * NTILE32 * LBUF);
    float* sel_score = (float*)(sel_idx + NB * NC * MAX_DET);

    compact_kernel<<<NB * NTILE32, 1024, 0, stream>>>(cls, tcnt_g, cand);
    nms_fused<<<NB * NC, NT, 0, stream>>>(boxes, cls, cand, tcnt_g,
                                          sel_idx, sel_score);
    topk_kernel<<<NB, 1024, 0, stream>>>(boxes, other, sel_idx, sel_score, out);
}

// Round 14
// 64.317 us; speedup vs baseline: 1.9967x; 1.0442x over previous
//
#include <hip/hip_runtime.h>
#include <math.h>
#include <stdint.h>

#define NB 16
#define NN 50000
#define NC 8
#define ND 2
#define MAX_DET 300
#define NMS_T 0.5f
#define SCORE_T 0.05f
#define CAP 1024
#define CUTBIN 252        // s >= 0.984375 ; E[cnt]=781 +- 28
#define LBUF 128          // per-(class,tile) segment; E=24.4, +20 sigma
#define NTILE32 32
#define CHUNK 256
#define NT 1024
#define NPI (NN * NC)
#define F4PB (NPI / 4 / NTILE32)

typedef unsigned long long u64;

__device__ __forceinline__ float neg_inf() { return -__builtin_inff(); }

// Bit-exact IoU > 0.5, division-free (R11-validated). area_b passed in —
// computed with the identical _rn formula, so bits match the reference.
__device__ __forceinline__ bool iou_gt(float ax1, float ay1, float ax2, float ay2,
                                       float area_a,
                                       float bx1, float by1, float bx2, float by2,
                                       float area_b) {
    float x1 = fmaxf(ax1, bx1), y1 = fmaxf(ay1, by1);
    float x2 = fminf(ax2, bx2), y2 = fminf(ay2, by2);
    float inter = __fmul_rn(fmaxf(__fsub_rn(x2, x1), 0.0f),
                            fmaxf(__fsub_rn(y2, y1), 0.0f));
    float uni = __fsub_rn(__fadd_rn(area_a, area_b), inter);
    return inter > __fmul_rn(0.5f, fmaxf(uni, 1e-8f));
}

__device__ __forceinline__ u64 score_key(float s, int n) {
    unsigned u = __float_as_uint(s);
    u ^= (u & 0x80000000u) ? 0xFFFFFFFFu : 0x80000000u;
    return ((u64)u << 32) | (unsigned)(~(unsigned)n);
}

__device__ __forceinline__ u64 shfl_xor_u64(u64 v, int m) {
    unsigned lo = (unsigned)v, hi = (unsigned)(v >> 32);
    lo = __shfl_xor(lo, m, 64);
    hi = __shfl_xor(hi, m, 64);
    return ((u64)hi << 32) | lo;
}

// ---------------- C: tiled compaction, NO global atomics ------------------
__global__ __launch_bounds__(1024) void compact_kernel(
    const float* __restrict__ cls, int* __restrict__ tcnt_g,
    u64* __restrict__ cand)
{
    const int b = blockIdx.x >> 5, t32 = blockIdx.x & 31;
    const int tid = threadIdx.x;
    __shared__ u64 buf[8][LBUF];
    __shared__ int lcnt[8];
    if (tid < 8) lcnt[tid] = 0;
    __syncthreads();

    const float4* c4 = (const float4*)(cls + (size_t)b * NPI);
    const int f0 = t32 * F4PB, fend = f0 + F4PB;

    for (int f = f0 + tid; f < fend; f += 1024) {
        float4 v = c4[f];
        int cb = (f & 1) * 4;
        int n = f >> 1;
        float vv[4] = {v.x, v.y, v.z, v.w};
        #pragma unroll
        for (int k = 0; k < 4; ++k) {
            float s = vv[k];
            if (s > SCORE_T) {
                int bn = (int)(s * 256.0f); if (bn > 255) bn = 255;
                if (bn >= CUTBIN) {
                    int c = cb + k;
                    int pos = atomicAdd(&lcnt[c], 1);   // LDS only
                    if (pos < LBUF) buf[c][pos] = score_key(s, n);
                }
            }
        }
    }
    __syncthreads();
    {
        int c = tid >> 7, i = tid & (LBUF - 1);
        int m = lcnt[c];
        if (i < (m < LBUF ? m : LBUF))
            cand[(size_t)(((b * 8 + c) * NTILE32) + t32) * LBUF + i] = buf[c][i];
        if (i == 0) tcnt_g[(b * 8 + c) * NTILE32 + t32] = m;
    }
}

// ---------------- N: fused gather + sort + 256-chunk fixpoint greedy ------
__global__ __launch_bounds__(NT) void nms_fused(
    const float* __restrict__ boxes, const float* __restrict__ cls,
    const u64* __restrict__ cand, const int* __restrict__ tcnt_g,
    int* __restrict__ sel_idx, float* __restrict__ sel_score)
{
    const int bc = blockIdx.x;
    const int b = bc >> 3, c = bc & 7;
    const int tid = threadIdx.x;
    const int lane = tid & 63;
    const float4* bx4 = (const float4*)(boxes + (size_t)b * NN * 4);
    const float* sr = cls + (size_t)b * NN * NC + c;   // fallback only
    int* si = sel_idx + bc * MAX_DET;
    float* ss = sel_score + bc * MAX_DET;

    __shared__ u64 keys[CAP];                    // 8 KB
    __shared__ int tcnt_s[NTILE32], toff_s[NTILE32];
    __shared__ int sh_total, sh_ovf;
    __shared__ u64 M64[4][CHUNK];                // 8 KB lower-triangle rows
    __shared__ unsigned presup4[4][CHUNK];       // 4 KB
    __shared__ float4 cbox2[2][CHUNK];           // 8 KB
    __shared__ float  carea2[2][CHUNK];          // 2 KB
    __shared__ int    cidx2[2][CHUNK];           // 2 KB
    __shared__ float  cscore2[2][CHUNK];         // 2 KB
    __shared__ u64 accs4_s[4];
    __shared__ float4 abox[MAX_DET];             // 4.8 KB
    __shared__ float aarea[MAX_DET];             // 1.2 KB
    __shared__ unsigned bm[(NN + 31) / 32];      // 6.3 KB fallback bitmask
    __shared__ float rv[NT];                     // 4 KB
    __shared__ int   ri[NT];                     // 4 KB
    __shared__ float sboxsh[5];

    // ---- tile-count scan (wave 0) ----
    if (tid < 64) {
        int v = (lane < NTILE32) ? tcnt_g[bc * NTILE32 + lane] : 0;
        int incl = v;
        #pragma unroll
        for (int d = 1; d < 32; d <<= 1) {
            int o = __shfl_up(incl, d, 64);
            if (lane >= d) incl += o;
        }
        if (lane < NTILE32) { tcnt_s[lane] = v; toff_s[lane] = incl - v; }
        u64 ov = __ballot(lane < NTILE32 && v > LBUF);
        if (lane == 31) { sh_total = incl; sh_ovf = (ov != 0); }
    }
    __syncthreads();
    const int cnt = sh_total;
    const bool full_fb = sh_ovf || (cnt > CAP);
    const int inSet = cnt < CAP ? cnt : CAP;

    int n_acc = 0;
    if (!full_fb) {
        // ---- zero + flat gather into keys ----
        for (int i = tid; i < CAP; i += NT) keys[i] = 0ull;
        __syncthreads();
        for (int s = tid; s < NTILE32 * LBUF; s += NT) {
            int t = s >> 7, i = s & (LBUF - 1);
            if (i < tcnt_s[t])
                keys[toff_s[t] + i] = cand[(size_t)(bc * NTILE32 + t) * LBUF + i];
        }
        __syncthreads();

        // ===== hybrid reg/LDS bitonic sort (threads 0-511 own 2 keys) =====
        const int p0 = (tid >> 6) * 128 + lane, p1 = p0 + 64;
        u64 v0 = 0, v1 = 0;
        if (tid < 512) {
            v0 = keys[p0]; v1 = keys[p1];
            #pragma unroll
            for (int k = 2; k <= 128; k <<= 1) {
                #pragma unroll
                for (int j = k >> 1; j > 0; j >>= 1) {
                    if (j == 64) {
                        bool dir = ((p0 & k) == 0);
                        if ((v0 < v1) == dir) { u64 t = v0; v0 = v1; v1 = t; }
                    } else {
                        bool lower = ((lane & j) == 0);
                        bool dir0 = ((p0 & k) == 0);
                        bool dir1 = ((p1 & k) == 0);   // differs at k=64
                        u64 o0 = shfl_xor_u64(v0, j);
                        u64 mx0 = v0 > o0 ? v0 : o0, mn0 = v0 > o0 ? o0 : v0;
                        v0 = (lower == dir0) ? mx0 : mn0;
                        u64 o1 = shfl_xor_u64(v1, j);
                        u64 mx1 = v1 > o1 ? v1 : o1, mn1 = v1 > o1 ? o1 : v1;
                        v1 = (lower == dir1) ? mx1 : mn1;
                    }
                }
            }
        }
        __syncthreads();
        for (int k = 256; k <= CAP; k <<= 1) {
            if (tid < 512) { keys[p0] = v0; keys[p1] = v1; }
            __syncthreads();
            for (int j = k >> 1; j >= 128; j >>= 1) {
                if (tid < 512) {
                    int p = tid;
                    int i = 2 * p - (p & (j - 1));
                    int ix = i + j;
                    bool dir = ((i & k) == 0);
                    u64 a = keys[i], b2 = keys[ix];
                    if ((a < b2) == dir) { keys[i] = b2; keys[ix] = a; }
                }
                __syncthreads();
            }
            if (tid < 512) {
                v0 = keys[p0]; v1 = keys[p1];
                {
                    bool dir = ((p0 & k) == 0);
                    if ((v0 < v1) == dir) { u64 t = v0; v0 = v1; v1 = t; }
                }
                #pragma unroll
                for (int j = 32; j > 0; j >>= 1) {   // k>=256: (p1&k)==(p0&k)
                    bool lower = ((lane & j) == 0);
                    bool dir = ((p0 & k) == 0);
                    u64 o0 = shfl_xor_u64(v0, j);
                    u64 mx0 = v0 > o0 ? v0 : o0, mn0 = v0 > o0 ? o0 : v0;
                    v0 = (lower == dir) ? mx0 : mn0;
                    u64 o1 = shfl_xor_u64(v1, j);
                    u64 mx1 = v1 > o1 ? v1 : o1, mn1 = v1 > o1 ? o1 : v1;
                    v1 = (lower == dir) ? mx1 : mn1;
                }
            }
            __syncthreads();
        }
        if (tid < 512) { keys[p0] = v0; keys[p1] = v1; }
        __syncthreads();

        // ===== stage chunk 0 =====
        if (tid < CHUNK && tid < inSet) {
            u64 key = keys[tid];
            int idx = (int)(~(unsigned)key);
            unsigned u = (unsigned)(key >> 32);
            unsigned uo = (u & 0x80000000u) ? (u ^ 0x80000000u) : (~u);
            float4 bb = bx4[idx];
            cbox2[0][tid] = bb;
            carea2[0][tid] = __fmul_rn(__fsub_rn(bb.z, bb.x), __fsub_rn(bb.w, bb.y));
            cidx2[0][tid] = idx; cscore2[0][tid] = __uint_as_float(uo);
        }
        __syncthreads();

        int base = 0, cur = 0;
        while (n_acc < MAX_DET && base < inSet) {
            int m = inSet - base; if (m > CHUNK) m = CHUNK;

            // ---- phase A: presup (x8 batch) + 64-wide triangle segment ----
            {
                int i = tid & (CHUNK - 1);
                int q = tid >> 8;                    // 0..3
                if (i < m) {
                    float4 B = cbox2[cur][i];
                    float  Barea = carea2[cur][i];
                    unsigned p = 0;
                    int t = q;
                    for (; t + 28 < n_acc; t += 32) {
                        float4 A0 = abox[t];      float r0 = aarea[t];
                        float4 A1 = abox[t + 4];  float r1 = aarea[t + 4];
                        float4 A2 = abox[t + 8];  float r2 = aarea[t + 8];
                        float4 A3 = abox[t + 12]; float r3 = aarea[t + 12];
                        float4 A4 = abox[t + 16]; float r4 = aarea[t + 16];
                        float4 A5 = abox[t + 20]; float r5 = aarea[t + 20];
                        float4 A6 = abox[t + 24]; float r6 = aarea[t + 24];
                        float4 A7 = abox[t + 28]; float r7 = aarea[t + 28];
                        bool s0 = iou_gt(A0.x,A0.y,A0.z,A0.w,r0,B.x,B.y,B.z,B.w,Barea);
                        bool s1 = iou_gt(A1.x,A1.y,A1.z,A1.w,r1,B.x,B.y,B.z,B.w,Barea);
                        bool s2 = iou_gt(A2.x,A2.y,A2.z,A2.w,r2,B.x,B.y,B.z,B.w,Barea);
                        bool s3 = iou_gt(A3.x,A3.y,A3.z,A3.w,r3,B.x,B.y,B.z,B.w,Barea);
                        bool s4 = iou_gt(A4.x,A4.y,A4.z,A4.w,r4,B.x,B.y,B.z,B.w,Barea);
                        bool s5 = iou_gt(A5.x,A5.y,A5.z,A5.w,r5,B.x,B.y,B.z,B.w,Barea);
                        bool s6 = iou_gt(A6.x,A6.y,A6.z,A6.w,r6,B.x,B.y,B.z,B.w,Barea);
                        bool s7 = iou_gt(A7.x,A7.y,A7.z,A7.w,r7,B.x,B.y,B.z,B.w,Barea);
                        if (s0|s1|s2|s3|s4|s5|s6|s7) { p = 1; break; }
                    }
                    if (!p) {
                        for (; t < n_acc; t += 4) {
                            float4 A = abox[t];
                            if (iou_gt(A.x,A.y,A.z,A.w,aarea[t],
                                       B.x,B.y,B.z,B.w,Barea)) { p = 1; break; }
                        }
                    }
                    presup4[q][i] = p;
                    // triangle segment: j in [64q, 64q+64) ∩ [0, i)
                    u64 bits = 0;
                    int j0 = q * 64;
                    int jend = i - j0; if (jend > 64) jend = 64; if (jend < 0) jend = 0;
                    int jj = 0;
                    for (; jj + 7 < jend; jj += 8) {
                        int j = j0 + jj;
                        float4 A0 = cbox2[cur][j];     float r0 = carea2[cur][j];
                        float4 A1 = cbox2[cur][j + 1]; float r1 = carea2[cur][j + 1];
                        float4 A2 = cbox2[cur][j + 2]; float r2 = carea2[cur][j + 2];
                        float4 A3 = cbox2[cur][j + 3]; float r3 = carea2[cur][j + 3];
                        float4 A4 = cbox2[cur][j + 4]; float r4 = carea2[cur][j + 4];
                        float4 A5 = cbox2[cur][j + 5]; float r5 = carea2[cur][j + 5];
                        float4 A6 = cbox2[cur][j + 6]; float r6 = carea2[cur][j + 6];
                        float4 A7 = cbox2[cur][j + 7]; float r7 = carea2[cur][j + 7];
                        if (iou_gt(A0.x,A0.y,A0.z,A0.w,r0,B.x,B.y,B.z,B.w,Barea)) bits |= 1ull << jj;
                        if (iou_gt(A1.x,A1.y,A1.z,A1.w,r1,B.x,B.y,B.z,B.w,Barea)) bits |= 1ull << (jj+1);
                        if (iou_gt(A2.x,A2.y,A2.z,A2.w,r2,B.x,B.y,B.z,B.w,Barea)) bits |= 1ull << (jj+2);
                        if (iou_gt(A3.x,A3.y,A3.z,A3.w,r3,B.x,B.y,B.z,B.w,Barea)) bits |= 1ull << (jj+3);
                        if (iou_gt(A4.x,A4.y,A4.z,A4.w,r4,B.x,B.y,B.z,B.w,Barea)) bits |= 1ull << (jj+4);
                        if (iou_gt(A5.x,A5.y,A5.z,A5.w,r5,B.x,B.y,B.z,B.w,Barea)) bits |= 1ull << (jj+5);
                        if (iou_gt(A6.x,A6.y,A6.z,A6.w,r6,B.x,B.y,B.z,B.w,Barea)) bits |= 1ull << (jj+6);
                        if (iou_gt(A7.x,A7.y,A7.z,A7.w,r7,B.x,B.y,B.z,B.w,Barea)) bits |= 1ull << (jj+7);
                    }
                    for (; jj < jend; ++jj) {
                        int j = j0 + jj;
                        float4 A = cbox2[cur][j];
                        if (iou_gt(A.x,A.y,A.z,A.w,carea2[cur][j],
                                   B.x,B.y,B.z,B.w,Barea)) bits |= 1ull << jj;
                    }
                    M64[q][i] = bits;
                }
            }
            __syncthreads();

            // ---- phase B: wave-0 fixpoint resolve ∥ waves 4-7 gather next ----
            int nbase = base + m;
            if (tid < 64) {
                u64 Mr[4][4];
                unsigned pe[4];
                bool acc[4];
                #pragma unroll
                for (int cg = 0; cg < 4; ++cg) {
                    int i = cg * 64 + lane;
                    if (i < m) {
                        pe[cg] = presup4[0][i] | presup4[1][i] | presup4[2][i] | presup4[3][i];
                        #pragma unroll
                        for (int w = 0; w < 4; ++w) Mr[cg][w] = M64[w][i];
                    } else {
                        pe[cg] = 1u;
                        #pragma unroll
                        for (int w = 0; w < 4; ++w) Mr[cg][w] = 0ull;
                    }
                    acc[cg] = (pe[cg] == 0);
                }
                u64 a0 = __ballot(acc[0]), a1 = __ballot(acc[1]);
                u64 a2 = __ballot(acc[2]), a3 = __ballot(acc[3]);
                // Jacobi fixpoint: unique fixpoint == greedy; converges in <= m iters
                for (int it = 0; it < CHUNK + 1; ++it) {
                    #pragma unroll
                    for (int cg = 0; cg < 4; ++cg) {
                        u64 sup = (Mr[cg][0] & a0) | (Mr[cg][1] & a1)
                                | (Mr[cg][2] & a2) | (Mr[cg][3] & a3);
                        acc[cg] = (pe[cg] == 0) && (sup == 0ull);
                    }
                    u64 n0 = __ballot(acc[0]), n1 = __ballot(acc[1]);
                    u64 n2 = __ballot(acc[2]), n3 = __ballot(acc[3]);
                    bool same = (n0 == a0) && (n1 == a1) && (n2 == a2) && (n3 == a3);
                    a0 = n0; a1 = n1; a2 = n2; a3 = n3;
                    if (same) break;
                }
                if (lane == 0) { accs4_s[0] = a0; accs4_s[1] = a1;
                                 accs4_s[2] = a2; accs4_s[3] = a3; }
            } else if (tid >= 256 && tid < 512 && nbase < inSet) {
                int w = tid - 256;
                if (nbase + w < inSet) {
                    u64 key = keys[nbase + w];
                    int idx = (int)(~(unsigned)key);
                    unsigned u = (unsigned)(key >> 32);
                    unsigned uo = (u & 0x80000000u) ? (u ^ 0x80000000u) : (~u);
                    float4 bb = bx4[idx];
                    cbox2[cur ^ 1][w] = bb;
                    carea2[cur ^ 1][w] = __fmul_rn(__fsub_rn(bb.z, bb.x), __fsub_rn(bb.w, bb.y));
                    cidx2[cur ^ 1][w] = idx; cscore2[cur ^ 1][w] = __uint_as_float(uo);
                }
            }
            __syncthreads();

            // ---- phase C: rank + write accepted (cap 300) ----
            u64 a0 = accs4_s[0], a1 = accs4_s[1], a2 = accs4_s[2], a3 = accs4_s[3];
            int add = __popcll(a0) + __popcll(a1) + __popcll(a2) + __popcll(a3);
            if (tid < m) {
                int gg = tid >> 6, o = tid & 63;
                u64 aw = (gg == 0) ? a0 : (gg == 1) ? a1 : (gg == 2) ? a2 : a3;
                if ((aw >> o) & 1ull) {
                    int rank = 0;
                    if (gg > 0) rank += __popcll(a0);
                    if (gg > 1) rank += __popcll(a1);
                    if (gg > 2) rank += __popcll(a2);
                    rank += __popcll(aw & ((1ull << o) - 1ull));
                    int pos = n_acc + rank;
                    if (pos < MAX_DET) {
                        abox[pos] = cbox2[cur][tid]; aarea[pos] = carea2[cur][tid];
                        si[pos] = cidx2[cur][tid]; ss[pos] = cscore2[cur][tid];
                    }
                }
            }
            n_acc += add; if (n_acc > MAX_DET) n_acc = MAX_DET;
            base = nbase; cur ^= 1;
            __syncthreads();
        }
    }

    const bool part_fb = (!full_fb) && (n_acc < MAX_DET);

    if (full_fb || part_fb) {
        // ======== exact fallback: bitmask argmax loop ========
        const int BMW = (NN + 31) / 32;
        for (int i = tid; i < BMW; i += NT) bm[i] = 0u;
        __syncthreads();
        if (full_fb) {
            n_acc = 0;
        } else {
            for (int n = tid; n < NN; n += NT) {
                float4 bbn = bx4[n];
                float nb_area = __fmul_rn(__fsub_rn(bbn.z, bbn.x), __fsub_rn(bbn.w, bbn.y));
                int s = 0;
                for (int t = 0; t < n_acc; ++t) {
                    float4 A = abox[t];
                    if (iou_gt(A.x, A.y, A.z, A.w, aarea[t],
                               bbn.x, bbn.y, bbn.z, bbn.w, nb_area)) s = 1;
                }
                if (s) atomicOr(&bm[n >> 5], 1u << (n & 31));
            }
        }
        __syncthreads();

        for (int k = n_acc; k < MAX_DET; ++k) {
            float bv = neg_inf(); int bi = 0x7fffffff;
            for (int n = tid; n < NN; n += NT) {
                if (!((bm[n >> 5] >> (n & 31)) & 1u)) {
                    float v = sr[(size_t)n * NC];
                    if (v > SCORE_T && v > bv) { bv = v; bi = n; }
                }
            }
            rv[tid] = bv; ri[tid] = bi;
            __syncthreads();
            for (int s = NT / 2; s > 0; s >>= 1) {
                if (tid < s) {
                    float ov = rv[tid + s]; int oi = ri[tid + s];
                    if (ov > rv[tid] || (ov == rv[tid] && oi < ri[tid])) { rv[tid] = ov; ri[tid] = oi; }
                }
                __syncthreads();
            }
            float mval = rv[0]; int midx = ri[0];
            if (mval == neg_inf()) {
                for (int kk = k + tid; kk < MAX_DET; kk += NT) { si[kk] = 0; ss[kk] = neg_inf(); }
                break;
            }
            if (tid == 0) {
                si[k] = midx; ss[k] = mval;
                float4 sb = bx4[midx];
                sboxsh[0] = sb.x; sboxsh[1] = sb.y; sboxsh[2] = sb.z; sboxsh[3] = sb.w;
                sboxsh[4] = __fmul_rn(__fsub_rn(sb.z, sb.x), __fsub_rn(sb.w, sb.y));
            }
            __syncthreads();
            float ax1 = sboxsh[0], ay1 = sboxsh[1], ax2 = sboxsh[2], ay2 = sboxsh[3];
            float area_a = sboxsh[4];
            for (int n = tid; n < NN; n += NT) {
                float4 bbn = bx4[n];
                float nb_area = __fmul_rn(__fsub_rn(bbn.z, bbn.x), __fsub_rn(bbn.w, bbn.y));
                if (iou_gt(ax1, ay1, ax2, ay2, area_a,
                           bbn.x, bbn.y, bbn.z, bbn.w, nb_area))
                    atomicOr(&bm[n >> 5], 1u << (n & 31));
            }
            __syncthreads();
        }
    } else {
        for (int kk = n_acc + tid; kk < MAX_DET; kk += NT) { si[kk] = 0; ss[kk] = neg_inf(); }
    }
}

// ---------------- T: top-300 via 8-way merge of sorted class lists --------
__global__ __launch_bounds__(1024) void topk_kernel(
    const float* __restrict__ boxes, const float* __restrict__ other,
    const int* __restrict__ sel_idx, const float* __restrict__ sel_score,
    float* __restrict__ out)
{
    const int b = blockIdx.x;
    const int tid = threadIdx.x;
    __shared__ u64 keys[4096];

    for (int i = tid; i < 4096; i += 1024) {
        int c = i >> 9, o = i & 511;
        u64 key = 0ull;
        if (o < MAX_DET) {
            int m = c * MAX_DET + o;
            float v = sel_score[b * NC * MAX_DET + m];
            unsigned u = __float_as_uint(v);
            u ^= (u & 0x80000000u) ? 0xFFFFFFFFu : 0x80000000u;
            key = ((u64)u << 32) | (unsigned)(~(unsigned)m);
        }
        keys[i] = key;
    }

    for (int seg = 1024; seg <= 4096; seg <<= 1) {
        int half = seg >> 1;
        __syncthreads();
        {
            int p = tid;
            int s = p / (half >> 1), t = p % (half >> 1);
            int i0 = s * seg + half + t;
            int i1 = s * seg + seg - 1 - t;
            u64 a = keys[i0]; keys[i0] = keys[i1]; keys[i1] = a;
        }
        __syncthreads();
        for (int j = half; j > 0; j >>= 1) {
            for (int p = tid; p < 2048; p += 1024) {
                int i = 2 * p - (p & (j - 1));
                int ix = i + j;
                u64 a = keys[i], bq = keys[ix];
                if (a < bq) { keys[i] = bq; keys[ix] = a; }
            }
            if (j >= 128) __syncthreads(); else __threadfence_block();
        }
    }
    __syncthreads();

    const float4* bx4 = (const float4*)(boxes + (size_t)b * NN * 4);
    const float*  ot  = other + (size_t)b * NN * ND;
    float* ob = out;
    float* os = out + NB * MAX_DET * 4;
    float* ol = os + NB * MAX_DET;
    float* oo = ol + NB * MAX_DET;

    for (int k = tid; k < MAX_DET; k += 1024) {
        u64 key = keys[k];
        unsigned u = (unsigned)(key >> 32);
        unsigned uo = (u & 0x80000000u) ? (u ^ 0x80000000u) : (u ^ 0xFFFFFFFFu);
        float score = __uint_as_float(uo);
        bool valid = isfinite(score);
        float b0=-1.f,b1=-1.f,b2=-1.f,b3=-1.f,scv=-1.f,lab=-1.f,o0=-1.f,o1=-1.f;
        if (valid) {
            int m = (int)(~(unsigned)key);
            int c = m / MAX_DET, slot = m - c * MAX_DET;
            int n = sel_idx[(b * NC + c) * MAX_DET + slot];
            float4 bb = bx4[n];
            b0 = bb.x; b1 = bb.y; b2 = bb.z; b3 = bb.w;
            scv = score; lab = (float)c;
            o0 = ot[n * ND + 0]; o1 = ot[n * ND + 1];
        }
        int base = b * MAX_DET + k;
        ob[base * 4 + 0] = b0; ob[base * 4 + 1] = b1;
        ob[base * 4 + 2] = b2; ob[base * 4 + 3] = b3;
        os[base] = scv; ol[base] = lab;
        oo[base * 2 + 0] = o0; oo[base * 2 + 1] = o1;
    }
}

extern "C" void kernel_launch(void* const* d_in, const int* in_sizes, int n_in,
                              void* d_out, int out_size, void* d_ws, size_t ws_size,
                              hipStream_t stream) {
    const float* boxes = (const float*)d_in[0];
    const float* cls   = (const float*)d_in[1];
    const float* other = (const float*)d_in[2];
    float* out = (float*)d_out;

    // ws: tcnt[128*32] | cand[128*32*LBUF] u64 | sel_idx | sel_score
    int* tcnt_g = (int*)d_ws;
    u64* cand  = (u64*)(tcnt_g + NB * NC * NTILE32);
    int* sel_idx = (int*)(cand + (size_t)NB * NC * NTILE32 * LBUF);
    float* sel_score = (float*)(sel_idx + NB * NC * MAX_DET);

    compact_kernel<<<NB * NTILE32, 1024, 0, stream>>>(cls, tcnt_g, cand);
    nms_fused<<<NB * NC, NT, 0, stream>>>(boxes, cls, cand, tcnt_g,
                                          sel_idx, sel_score);
    topk_kernel<<<NB, 1024, 0, stream>>>(boxes, other, sel_idx, sel_score, out);
}